// Round 6
// baseline (163.998 us; speedup 1.0000x reference)
//
#include <hip/hip_runtime.h>

// EuclideanFastAttention — MI355X (gfx950)
// A = (1/6) qr·kr^T per batch (256x256, K=6912, split by grid dir g=6), out = A·v.
// R19 = R18 + SLAB RELAYOUT of qr/kr: [g][m][node][128] instead of [g][node][1152].
// k_qkv's dominant 120MB write stream becomes 6x16KB contiguous blocks per WG
// (was 256B bursts at 2304B stride => DRAM row-buffer thrash, the last
// un-eliminated suspect after VALU/occupancy/barrier/inst-count all nulled).
// gemm1 reads get denser too (128B per 256B vs 128B per 2304B); A is identical
// under the kk = m*128+j relabeling.
// Alias: A2 -> OFF_QR (qr dead after gemm1).  High-water = OFF_AP + 25.2MB = 148.2MB.

typedef unsigned short u16;
typedef __attribute__((ext_vector_type(8))) short short8;   // 8 x bf16 bits (MFMA frag)
typedef __attribute__((ext_vector_type(4))) float f32x4;    // MFMA acc

static constexpr int N_NODES = 4096;
static constexpr int NBATCH  = 16;
static constexpr int NB      = 256;
static constexpr int NDEG    = 9;
static constexpr int MD      = NDEG * 128;    // 1152
static constexpr int KTOT    = 6 * MD;        // 6912
static constexpr size_t ASLICE = (size_t)NBATCH * NB * NB;   // elems per partial slice

// ws layout (bytes), aliased along the kernel timeline
static constexpr size_t OFF_WT  = 0;                                  // 9*16384 bf16
static constexpr size_t OFF_QR  = OFF_WT  + (size_t)9*16384*2;        // [g][m][n][128] 56.6MB
static constexpr size_t OFF_KR  = OFF_QR  + (size_t)N_NODES*KTOT*2;   // 56.6MB
static constexpr size_t OFF_VT  = OFF_KR  + (size_t)N_NODES*KTOT*2;   // [d][n] 9.4MB
static constexpr size_t OFF_AP  = OFF_VT  + (size_t)N_NODES*MD*2;     // 12*16*65536*2 = 25.2MB
static constexpr size_t OFF_A2  = OFF_QR;                             // alias (2.1MB)

__device__ inline u16 f2bf(float x) {
    union { float f; unsigned u; } v; v.f = x;
    unsigned r = v.u + 0x7fffu + ((v.u >> 16) & 1u);   // RNE
    return (u16)(r >> 16);
}
__device__ inline float bf2f(u16 h) {
    union { unsigned u; float f; } v; v.u = ((unsigned)h) << 16; return v.f;
}
__device__ inline unsigned pk2bf(float a, float b) {
#if __has_builtin(__builtin_amdgcn_cvt_pk_bf16_f32)
    typedef __attribute__((ext_vector_type(2))) __bf16 bf2_t;
    union { bf2_t v; unsigned u; } cv;
    cv.v = __builtin_amdgcn_cvt_pk_bf16_f32(a, b);
    return cv.u;
#else
    return (unsigned)f2bf(a) | ((unsigned)f2bf(b) << 16);
#endif
}

// async global->LDS, 16B per lane; LDS dest = wave-uniform base + lane*16 (HW rule).
__device__ __forceinline__ void gl2lds16(const u16* g, u16* l) {
#if __has_builtin(__builtin_amdgcn_global_load_lds)
    __builtin_amdgcn_global_load_lds(
        (const __attribute__((address_space(1))) unsigned int*)g,
        (__attribute__((address_space(3))) unsigned int*)l, 16, 0, 0);
#else
    int lane = threadIdx.x & 63;
    *(uint4*)(l + lane * 8) = *(const uint4*)g;
#endif
}

// ---------------- kernel 1: W transpose + bf16 cast --------------------------
// wt[(mat*3+l)][j][f] = W[l][f][j];  grid 36 = 9 blk x 4 tiles
__global__ __launch_bounds__(256) void k_prep(const float* __restrict__ Wq,
                                              const float* __restrict__ Wk,
                                              const float* __restrict__ Wv,
                                              u16* __restrict__ wt) {
    int t = blockIdx.x, tid = threadIdx.x;
    int blk = t >> 2, tt = t & 3;
    int mat = blk / 3, l = blk % 3;
    const float* W = (mat == 0 ? Wq : (mat == 1 ? Wk : Wv)) + (size_t)l * 16384;
    int j0 = (tt >> 1) * 64, f0 = (tt & 1) * 64;
    __shared__ u16 tile[64 * 72];
    for (int e = tid; e < 1024; e += 256) {
        int r = e >> 4, c = e & 15;
        float4 wv = *(const float4*)(W + (size_t)(f0 + r) * 128 + j0 + c * 4);
        tile[(c * 4 + 0) * 72 + r] = f2bf(wv.x);
        tile[(c * 4 + 1) * 72 + r] = f2bf(wv.y);
        tile[(c * 4 + 2) * 72 + r] = f2bf(wv.z);
        tile[(c * 4 + 3) * 72 + r] = f2bf(wv.w);
    }
    __syncthreads();
    u16* dst = wt + (size_t)blk * 16384;
    for (int e = tid; e < 512; e += 256) {
        int j = e >> 3, c = e & 7;
        *(uint4*)(dst + (size_t)(j0 + j) * 128 + f0 + c * 8) = *(const uint4*)(tile + j * 72 + c * 8);
    }
}

// ---------------- kernel 2: dense(q/k/v) + bias + RoPE -----------------------
// grid (64 node-tiles, 9 m, 3 mats).  W staged in 2 x 64-row halves (~36KB LDS).
// mats 0/1: swapped-operand MFMA -> feature-major lanes -> lean in-lane RoPE,
// stores 6 x 16KB CONTIGUOUS slabs (R19).  mat 2: original path (vt transpose).
__global__ __launch_bounds__(256) void k_qkv(const float* __restrict__ X,
                                             const u16* __restrict__ wt,
                                             const float* __restrict__ bq,
                                             const float* __restrict__ bk,
                                             const float* __restrict__ bv,
                                             const float* __restrict__ pos,
                                             u16* __restrict__ qr,
                                             u16* __restrict__ kr,
                                             u16* __restrict__ vt) {
    const int nt = blockIdx.x, m = blockIdx.y, mat = blockIdx.z;
    const int n0 = nt * 64;
    const int deg = (m == 0) ? 0 : (m < 4 ? 1 : 2);
    const int tid = threadIdx.x;

    __shared__ u16 smem[2 * 64 * 144];   // Xs(64x136) ++ Ws(64x136); O0/O1 at stride 144
    __shared__ float posS[192];          // pos[n0..n0+63][3]
    u16* Xs = smem;
    u16* Ws = smem + 64 * 136;

    if (tid < 192) posS[tid] = pos[(size_t)n0 * 3 + tid];

    for (int e = tid; e < 2048; e += 256) {            // stage X (fp32->bf16, HW pk)
        int r = e >> 5, f4 = e & 31;
        float4 xv = *(const float4*)(X + (size_t)(n0 + r) * MD + m * 128 + f4 * 4);
        uint2 o = make_uint2(pk2bf(xv.x, xv.y), pk2bf(xv.z, xv.w));
        *(uint2*)(Xs + r * 136 + f4 * 4) = o;
    }
    const uint4* wsrc = (const uint4*)(wt + (size_t)(mat * 3 + deg) * 16384);
    for (int e = tid; e < 1024; e += 256) {            // stage W half 0 (rows 0..63)
        int j = e >> 4, f8 = e & 15;
        *(uint4*)(Ws + j * 136 + f8 * 8) = wsrc[j * 16 + f8];
    }
    __syncthreads();

    const int w = tid >> 6, lane = tid & 63, quad = lane >> 4, lrow = lane & 15;

    if (mat == 2) {                    // ---- v path (original operand order) ----
        f32x4 acc[8];
#pragma unroll
        for (int ct = 0; ct < 8; ct++) acc[ct] = (f32x4){0.f, 0.f, 0.f, 0.f};
        for (int h = 0; h < 2; h++) {
            if (h) {
                for (int e = tid; e < 1024; e += 256) {
                    int j = e >> 4, f8 = e & 15;
                    *(uint4*)(Ws + j * 136 + f8 * 8) = wsrc[(64 + j) * 16 + f8];
                }
                __syncthreads();
            }
#pragma unroll
            for (int ks = 0; ks < 4; ks++) {
                short8 a = *(const short8*)(Xs + (w * 16 + lrow) * 136 + ks * 32 + quad * 8);
#pragma unroll
                for (int c4 = 0; c4 < 4; c4++) {
                    short8 bfr = *(const short8*)(Ws + (c4 * 16 + lrow) * 136 + ks * 32 + quad * 8);
                    acc[h * 4 + c4] = __builtin_amdgcn_mfma_f32_16x16x32_bf16(a, bfr, acc[h * 4 + c4], 0, 0, 0);
                }
            }
            if (!h) __syncthreads();
        }
        float yv[8][4];
#pragma unroll
        for (int ct = 0; ct < 8; ct++)
#pragma unroll
            for (int r = 0; r < 4; r++) yv[ct][r] = acc[ct][r];

        u16* T = Ws;                   // 128 x 66
        const int nlb = w * 16 + quad * 4;
        __syncthreads();
#pragma unroll
        for (int ct = 0; ct < 8; ct++) {
            int j = ct * 16 + lrow;
            *(unsigned*)(T + j * 66 + nlb)     = pk2bf(yv[ct][0], yv[ct][1]);
            *(unsigned*)(T + j * 66 + nlb + 2) = pk2bf(yv[ct][2], yv[ct][3]);
        }
        __syncthreads();
        for (int e = tid; e < 1024; e += 256) {
            int d = e >> 3, c = e & 7;
            *(uint4*)(vt + (size_t)(m * 128 + d) * N_NODES + n0 + c * 8) =
                *(const uint4*)(T + d * 66 + c * 8);
        }
        return;
    }

    // ---- q/k path: swapped operands => C rows = features, cols = nodes ----
    f32x4 acc[8];
#pragma unroll
    for (int ct = 0; ct < 8; ct++) acc[ct] = (f32x4){0.f, 0.f, 0.f, 0.f};
    for (int h = 0; h < 2; h++) {
        if (h) {
            for (int e = tid; e < 1024; e += 256) {
                int j = e >> 4, f8 = e & 15;
                *(uint4*)(Ws + j * 136 + f8 * 8) = wsrc[(64 + j) * 16 + f8];
            }
            __syncthreads();
        }
#pragma unroll
        for (int ks = 0; ks < 4; ks++) {
            short8 bx = *(const short8*)(Xs + (w * 16 + lrow) * 136 + ks * 32 + quad * 8);
#pragma unroll
            for (int c4 = 0; c4 < 4; c4++) {
                short8 aw = *(const short8*)(Ws + (c4 * 16 + lrow) * 136 + ks * 32 + quad * 8);
                acc[h * 4 + c4] = __builtin_amdgcn_mfma_f32_16x16x32_bf16(aw, bx, acc[h * 4 + c4], 0, 0, 0);
            }
        }
        if (!h) __syncthreads();
    }

    // lane holds features f = ct*16 + quad*4 + r (r=0..3) of node w*16+lrow
    const float* bias = (mat == 0) ? bq : bk;
    float yv[8][4];
#pragma unroll
    for (int ct = 0; ct < 8; ct++) {
        float4 b4 = (m == 0) ? *(const float4*)(bias + ct * 16 + quad * 4)
                             : make_float4(0.f, 0.f, 0.f, 0.f);
        yv[ct][0] = acc[ct][0] + b4.x;
        yv[ct][1] = acc[ct][1] + b4.y;
        yv[ct][2] = acc[ct][2] + b4.z;
        yv[ct][3] = acc[ct][3] + b4.w;
    }

    const int node = w * 16 + lrow;
    float p3[3];
#pragma unroll
    for (int gp = 0; gp < 3; gp++) p3[gp] = posS[node * 3 + gp];

    u16* O0 = smem;                    // 64 x 144
    u16* O1 = smem + 64 * 144;
    u16* dst = (mat == 0) ? qr : kr;
    const float K8 = 8.0f / 630.0f;
    const size_t GSTRIDE = (size_t)NDEG * N_NODES * 128;   // one g slab

    __syncthreads();                   // all waves done with Xs/Ws before overwrite

    for (int gp = 0; gp < 3; gp++) {
        float p = p3[gp];
#pragma unroll
        for (int ct = 0; ct < 8; ct++) {
            float ti = (float)(ct * 8 + quad * 2) * K8;   // theta for pair 0
            float s0, c0, s1, c1;
            __sincosf(p * ti, &s0, &c0);
            __sincosf(p * (ti + K8), &s1, &c1);
            float y0 = yv[ct][0], y1 = yv[ct][1], y2 = yv[ct][2], y3 = yv[ct][3];
            // +dir: out_even = y0 c - y1 s ; out_odd = y1 c + y0 s
            unsigned w0p = pk2bf(y0 * c0 - y1 * s0, y1 * c0 + y0 * s0);
            unsigned w1p = pk2bf(y2 * c1 - y3 * s1, y3 * c1 + y2 * s1);
            // -dir (sin -> -sin)
            unsigned w0m = pk2bf(y0 * c0 + y1 * s0, y1 * c0 - y0 * s0);
            unsigned w1m = pk2bf(y2 * c1 + y3 * s1, y3 * c1 - y2 * s1);
            int off = node * 144 + ct * 16 + quad * 4;    // 8B-aligned
            *(uint2*)(O0 + off) = make_uint2(w0p, w1p);
            *(uint2*)(O1 + off) = make_uint2(w0m, w1m);
        }
        // wave-local store: contiguous 16KB slab per (gp,dir) across the block
        size_t sb = ((size_t)(gp * 2 * NDEG + m) * N_NODES + n0) * 128;
#pragma unroll
        for (int it = 0; it < 4; it++) {
            int slot = it * 64 + lane;
            int nl = w * 16 + (slot >> 4), cc = slot & 15;
            size_t o0 = sb + (size_t)nl * 128 + cc * 8;
            *(uint4*)(dst + o0)           = *(const uint4*)(O0 + nl * 144 + cc * 8);
            *(uint4*)(dst + o0 + GSTRIDE) = *(const uint4*)(O1 + nl * 144 + cc * 8);
        }
    }
}

// ---------------- kernel 3: Apart[g*2+kh] = qr_g · kr_g^T  (128x128, Ksplit2) ----
// 768 blocks = 96 (b,g) x 4 tiles x 2 k-halves = 3 blocks/CU exactly.
// Slab layout: per kc, m-slab = kk>>7, sub = kk&127; row stride 128 (256B dense).
// Staging: global_load_lds 16B/lane into linear LDS [128][64]; sigma2 swizzle
// (col ^= ((row>>2)&3)<<4) pre-applied on the GLOBAL source and on frag READS.
__global__ __launch_bounds__(256) void k_gemm1(const u16* __restrict__ qr,
                                               const u16* __restrict__ kr,
                                               u16* __restrict__ Apart) {
    int idx = blockIdx.x;              // 0..767
    int c   = idx & 7;                 // XCD id under round-robin-8
    int u   = idx >> 3;                // 0..95
    int t   = u & 3;                   // tile within combo
    int combo = (u >> 2) * 8 + c;      // 0..191
    int kh  = combo & 1;
    int bg  = combo >> 1;              // 0..95
    int g   = bg >> 4, b = bg & 15;
    int tr  = t >> 1, tc = t & 1;

    int qn0 = b * NB + tr * 128, kn0 = b * NB + tc * 128;
    int tid = threadIdx.x;
    __shared__ u16 Qs[128 * 64];       // linear, swizzled content
    __shared__ u16 Ks[128 * 64];
    int w = tid >> 6, lane = tid & 63, quad = lane >> 4, lrow = lane & 15;
    int l8 = lane >> 3, c8 = (lane & 7) * 8, lhi = lane >> 5;

    f32x4 acc[2][8];
#pragma unroll
    for (int at = 0; at < 2; at++)
#pragma unroll
        for (int ct = 0; ct < 8; ct++) acc[at][ct] = (f32x4){0.f, 0.f, 0.f, 0.f};

    u16* qdst = Qs + w * 32 * 64;      // wave-uniform LDS bases
    u16* kdst = Ks + w * 32 * 64;
    const int fs = ((lrow >> 2) & 3) << 4;   // frag-read swizzle (row-dependent via lrow)

    for (int kc = 0; kc < 9; kc++) {   // K half = 576 = 9 x 64
        int kk = kh * 576 + kc * 64;   // global k in 0..1151
        int ms = kk >> 7, sub = kk & 127;
        const u16* qb = qr + ((size_t)(g * NDEG + ms) * N_NODES + qn0) * 128 + sub;
        const u16* kb = kr + ((size_t)(g * NDEG + ms) * N_NODES + kn0) * 128 + sub;
#pragma unroll
        for (int s = 0; s < 4; s++) {  // wave w stages rows w*32+s*8 .. +8 of Q and K
            int row = w * 32 + s * 8 + l8;
            int sc  = c8 ^ (((2 * s + lhi) & 3) << 4);   // sigma2 on source col
            gl2lds16(qb + (size_t)row * 128 + sc, qdst + s * 8 * 64);
            gl2lds16(kb + (size_t)row * 128 + sc, kdst + s * 8 * 64);
        }
        __syncthreads();               // drains vmcnt(0) incl. global_load_lds
#pragma unroll
        for (int ks = 0; ks < 2; ks++) {
            int cs = (ks * 32 + quad * 8) ^ fs;
            int r0 = w * 32 + lrow;
            short8 a0 = *(const short8*)(Qs + r0 * 64 + cs);
            short8 a1 = *(const short8*)(Qs + (r0 + 16) * 64 + cs);
#pragma unroll
            for (int ct = 0; ct < 8; ct++) {
                short8 bfr = *(const short8*)(Ks + (ct * 16 + lrow) * 64 + cs);
                acc[0][ct] = __builtin_amdgcn_mfma_f32_16x16x32_bf16(a0, bfr, acc[0][ct], 0, 0, 0);
                acc[1][ct] = __builtin_amdgcn_mfma_f32_16x16x32_bf16(a1, bfr, acc[1][ct], 0, 0, 0);
            }
        }
        __syncthreads();
    }
    u16* dst = Apart + ((size_t)(g * 2 + kh) * NBATCH + b) * (NB * NB);
#pragma unroll
    for (int at = 0; at < 2; at++)
#pragma unroll
        for (int ct = 0; ct < 8; ct++)
#pragma unroll
            for (int r = 0; r < 4; r++) {
                int rib = tr * 128 + w * 32 + at * 16 + quad * 4 + r;
                int cib = tc * 128 + ct * 16 + lrow;
                dst[(size_t)rib * NB + cib] = f2bf(acc[at][ct][r]);
            }
}

// ---------------- kernel 3b: A2 = (1/6) sum_{12 partials} Apart[s]  (bf16) ---
__global__ __launch_bounds__(256) void k_asum(const u16* __restrict__ Ap,
                                              u16* __restrict__ A2) {
    size_t t = (size_t)blockIdx.x * 256 + threadIdx.x;   // uint4 index, < 131072
    float sacc[8];
#pragma unroll
    for (int i = 0; i < 8; i++) sacc[i] = 0.f;
#pragma unroll
    for (int s = 0; s < 12; s++) {
        uint4 v = *(const uint4*)(Ap + (size_t)s * ASLICE + t * 8);
        const unsigned* uu = (const unsigned*)&v;
#pragma unroll
        for (int h = 0; h < 4; h++) {
            sacc[h * 2]     += bf2f((u16)(uu[h] & 0xffff));
            sacc[h * 2 + 1] += bf2f((u16)(uu[h] >> 16));
        }
    }
    const float sc6 = 1.0f / 6.0f;
    unsigned o32[4];
#pragma unroll
    for (int i = 0; i < 4; i++) o32[i] = pk2bf(sacc[i * 2] * sc6, sacc[i * 2 + 1] * sc6);
    *(uint4*)(A2 + t * 8) = *(const uint4*)o32;
}

// ---------------- kernel 4: out = A2 · v  (+mask) ----------------------------
// 576 blocks 1-D, XCD-decoded: XCD c owns 8 (rt,b) pairs x all 9 dcb, so the
// 9 dcb blocks re-read their A-strip (32KB) from c's L2.
__global__ __launch_bounds__(256) void k_gemm2(const u16* __restrict__ A2,
                                               const u16* __restrict__ vt,
                                               const int* __restrict__ gmask,
                                               float* __restrict__ out) {
    int idx = blockIdx.x;              // 0..575
    int c   = idx & 7;                 // XCD id under round-robin-8
    int u   = idx >> 3;                // 0..71
    int pr9 = u / 9;                   // 0..7
    int dcb = u - pr9 * 9;             // 0..8
    int pair = pr9 * 8 + c;            // 0..63
    int rt  = pair >> 4, b = pair & 15;
    int d0 = dcb * 128;
    int tid = threadIdx.x;
    __shared__ u16 As[64 * 72];
    __shared__ u16 Vs[128 * 72];
    int w = tid >> 6, lane = tid & 63, quad = lane >> 4, lrow = lane & 15;

    f32x4 acc[8];
#pragma unroll
    for (int ct = 0; ct < 8; ct++) acc[ct] = (f32x4){0.f, 0.f, 0.f, 0.f};

    for (int kc = 0; kc < 4; kc++) {
        int k0 = kc * 64;
#pragma unroll
        for (int e = tid; e < 512; e += 256) {     // A: direct copy (summed upstream)
            int r = e >> 3, c8 = e & 7;
            *(uint4*)(As + r * 72 + c8 * 8) =
                *(const uint4*)(A2 + (size_t)b * (NB * NB) + (size_t)(rt * 64 + r) * NB + k0 + c8 * 8);
        }
#pragma unroll
        for (int e = tid; e < 1024; e += 256) {
            int rr = e >> 3, sc2 = e & 7;
            *(uint4*)(Vs + rr * 72 + sc2 * 8) =
                *(const uint4*)(vt + (size_t)(d0 + rr) * N_NODES + b * NB + k0 + sc2 * 8);
        }
        __syncthreads();
#pragma unroll
        for (int ks = 0; ks < 2; ks++) {
            short8 a = *(const short8*)(As + (w * 16 + lrow) * 72 + ks * 32 + quad * 8);
#pragma unroll
            for (int ct = 0; ct < 8; ct++) {
                short8 bfr = *(const short8*)(Vs + (ct * 16 + lrow) * 72 + ks * 32 + quad * 8);
                acc[ct] = __builtin_amdgcn_mfma_f32_16x16x32_bf16(a, bfr, acc[ct], 0, 0, 0);
            }
        }
        __syncthreads();
    }
    int mv = gmask[b];
#pragma unroll
    for (int ct = 0; ct < 8; ct++)
#pragma unroll
        for (int r = 0; r < 4; r++) {
            int node = b * NB + rt * 64 + w * 16 + quad * 4 + r;
            int d = d0 + ct * 16 + lrow;
            out[(size_t)node * MD + d] = mv ? acc[ct][r] : 0.0f;
        }
}

// ---------------- launch -----------------------------------------------------
extern "C" void kernel_launch(void* const* d_in, const int* in_sizes, int n_in,
                              void* d_out, int out_size, void* d_ws, size_t ws_size,
                              hipStream_t stream) {
    (void)in_sizes; (void)n_in; (void)out_size; (void)ws_size;

    const float* X    = (const float*)d_in[0];
    const float* pos  = (const float*)d_in[1];
    const int*   gmask= (const int*)  d_in[3];
    const float* Wq   = (const float*)d_in[4];
    const float* bq   = (const float*)d_in[5];
    const float* Wk   = (const float*)d_in[6];
    const float* bk   = (const float*)d_in[7];
    const float* Wv   = (const float*)d_in[8];
    const float* bv   = (const float*)d_in[9];
    float* out = (float*)d_out;
    (void)bv;

    char* ws = (char*)d_ws;
    u16*   wt   = (u16*)  (ws + OFF_WT);
    u16*   qrp  = (u16*)  (ws + OFF_QR);
    u16*   krp  = (u16*)  (ws + OFF_KR);
    u16*   vtp  = (u16*)  (ws + OFF_VT);
    u16*   App  = (u16*)  (ws + OFF_AP);
    u16*   a2p  = (u16*)  (ws + OFF_A2);    // alias of qrp (timeline-disjoint)

    k_prep <<<dim3(36),         dim3(256), 0, stream>>>(Wq, Wk, Wv, wt);
    k_qkv  <<<dim3(64, 9, 3),   dim3(256), 0, stream>>>(X, wt, bq, bk, bv, pos, qrp, krp, vtp);
    k_gemm1<<<dim3(768),        dim3(256), 0, stream>>>(qrp, krp, App);
    k_asum <<<dim3(512),        dim3(256), 0, stream>>>(App, a2p);
    k_gemm2<<<dim3(576),        dim3(256), 0, stream>>>(a2p, vtp, gmask, out);
}

// Round 8
// 158.432 us; speedup vs baseline: 1.0351x; 1.0351x over previous
//
#include <hip/hip_runtime.h>

// EuclideanFastAttention — MI355X (gfx950)
// A = (1/6) qr·kr^T per batch (256x256, K=6912, split by grid dir g=6), out = A·v.
// R21 = R20 resubmission (prior round died to infra: "container failed twice";
// bounds + swizzle re-audited, no kernel-side cause found).
// R20 = R19 + (a) qkv O-stride 144->136 (R18 regression: stride 144 = 4-way bank
//             conflict on every b64 write; 136 => dw-stride 68 == 4 mod 32 => free)
//           + (b) k_gemm2 staging ported to gemm1's proven global_load_lds(16B)
//             + sigma2 swizzle pattern (was reg-staged scalar copies).
// Budget note (R20 analysis): ~85us of dur_us is harness ws-poison fill + restore
// dispatches (256MiB fills @ ~41us visible in top-5) — not controllable. Kernel
// budget ~79us: qkv 43 (at its mixed-R/W memory rate; 6 structural theories nulled),
// gemm1 ~18 (HBM floor: 113MB unique / 6.3TB/s), gemm2 ~11 -> target ~8, asum 4.5.
// Alias: A2 -> OFF_QR (qr dead after gemm1).  High-water = OFF_AP + 25.2MB = 148.2MB.

typedef unsigned short u16;
typedef __attribute__((ext_vector_type(8))) short short8;   // 8 x bf16 bits (MFMA frag)
typedef __attribute__((ext_vector_type(4))) float f32x4;    // MFMA acc

static constexpr int N_NODES = 4096;
static constexpr int NBATCH  = 16;
static constexpr int NB      = 256;
static constexpr int NDEG    = 9;
static constexpr int MD      = NDEG * 128;    // 1152
static constexpr int KTOT    = 6 * MD;        // 6912
static constexpr size_t ASLICE = (size_t)NBATCH * NB * NB;   // elems per partial slice

// ws layout (bytes), aliased along the kernel timeline
static constexpr size_t OFF_WT  = 0;                                  // 9*16384 bf16
static constexpr size_t OFF_QR  = OFF_WT  + (size_t)9*16384*2;        // [g][m][n][128] 56.6MB
static constexpr size_t OFF_KR  = OFF_QR  + (size_t)N_NODES*KTOT*2;   // 56.6MB
static constexpr size_t OFF_VT  = OFF_KR  + (size_t)N_NODES*KTOT*2;   // [d][n] 9.4MB
static constexpr size_t OFF_AP  = OFF_VT  + (size_t)N_NODES*MD*2;     // 12*16*65536*2 = 25.2MB
static constexpr size_t OFF_A2  = OFF_QR;                             // alias (2.1MB)

__device__ inline u16 f2bf(float x) {
    union { float f; unsigned u; } v; v.f = x;
    unsigned r = v.u + 0x7fffu + ((v.u >> 16) & 1u);   // RNE
    return (u16)(r >> 16);
}
__device__ inline float bf2f(u16 h) {
    union { unsigned u; float f; } v; v.u = ((unsigned)h) << 16; return v.f;
}
__device__ inline unsigned pk2bf(float a, float b) {
#if __has_builtin(__builtin_amdgcn_cvt_pk_bf16_f32)
    typedef __attribute__((ext_vector_type(2))) __bf16 bf2_t;
    union { bf2_t v; unsigned u; } cv;
    cv.v = __builtin_amdgcn_cvt_pk_bf16_f32(a, b);
    return cv.u;
#else
    return (unsigned)f2bf(a) | ((unsigned)f2bf(b) << 16);
#endif
}

// async global->LDS, 16B per lane; LDS dest = wave-uniform base + lane*16 (HW rule).
__device__ __forceinline__ void gl2lds16(const u16* g, u16* l) {
#if __has_builtin(__builtin_amdgcn_global_load_lds)
    __builtin_amdgcn_global_load_lds(
        (const __attribute__((address_space(1))) unsigned int*)g,
        (__attribute__((address_space(3))) unsigned int*)l, 16, 0, 0);
#else
    int lane = threadIdx.x & 63;
    *(uint4*)(l + lane * 8) = *(const uint4*)g;
#endif
}

// ---------------- kernel 1: W transpose + bf16 cast --------------------------
// wt[(mat*3+l)][j][f] = W[l][f][j];  grid 36 = 9 blk x 4 tiles
__global__ __launch_bounds__(256) void k_prep(const float* __restrict__ Wq,
                                              const float* __restrict__ Wk,
                                              const float* __restrict__ Wv,
                                              u16* __restrict__ wt) {
    int t = blockIdx.x, tid = threadIdx.x;
    int blk = t >> 2, tt = t & 3;
    int mat = blk / 3, l = blk % 3;
    const float* W = (mat == 0 ? Wq : (mat == 1 ? Wk : Wv)) + (size_t)l * 16384;
    int j0 = (tt >> 1) * 64, f0 = (tt & 1) * 64;
    __shared__ u16 tile[64 * 72];
    for (int e = tid; e < 1024; e += 256) {
        int r = e >> 4, c = e & 15;
        float4 wv = *(const float4*)(W + (size_t)(f0 + r) * 128 + j0 + c * 4);
        tile[(c * 4 + 0) * 72 + r] = f2bf(wv.x);
        tile[(c * 4 + 1) * 72 + r] = f2bf(wv.y);
        tile[(c * 4 + 2) * 72 + r] = f2bf(wv.z);
        tile[(c * 4 + 3) * 72 + r] = f2bf(wv.w);
    }
    __syncthreads();
    u16* dst = wt + (size_t)blk * 16384;
    for (int e = tid; e < 512; e += 256) {
        int j = e >> 3, c = e & 7;
        *(uint4*)(dst + (size_t)(j0 + j) * 128 + f0 + c * 8) = *(const uint4*)(tile + j * 72 + c * 8);
    }
}

// ---------------- kernel 2: dense(q/k/v) + bias + RoPE -----------------------
// grid (64 node-tiles, 9 m, 3 mats).  W staged in 2 x 64-row halves (~35KB LDS).
// mats 0/1: swapped-operand MFMA -> feature-major lanes -> in-lane RoPE,
// contiguous 16KB slab stores (R19).  O-stride 136 (conflict-free b64, R20).
// mat 2: original node-major path (vt transpose).
__global__ __launch_bounds__(256) void k_qkv(const float* __restrict__ X,
                                             const u16* __restrict__ wt,
                                             const float* __restrict__ bq,
                                             const float* __restrict__ bk,
                                             const float* __restrict__ bv,
                                             const float* __restrict__ pos,
                                             u16* __restrict__ qr,
                                             u16* __restrict__ kr,
                                             u16* __restrict__ vt) {
    const int nt = blockIdx.x, m = blockIdx.y, mat = blockIdx.z;
    const int n0 = nt * 64;
    const int deg = (m == 0) ? 0 : (m < 4 ? 1 : 2);
    const int tid = threadIdx.x;

    __shared__ u16 smem[2 * 64 * 136];   // Xs(64x136) ++ Ws(64x136); reused as O0/O1/T
    __shared__ float posS[192];          // pos[n0..n0+63][3]
    u16* Xs = smem;
    u16* Ws = smem + 64 * 136;

    if (tid < 192) posS[tid] = pos[(size_t)n0 * 3 + tid];

    for (int e = tid; e < 2048; e += 256) {            // stage X (fp32->bf16, HW pk)
        int r = e >> 5, f4 = e & 31;
        float4 xv = *(const float4*)(X + (size_t)(n0 + r) * MD + m * 128 + f4 * 4);
        uint2 o = make_uint2(pk2bf(xv.x, xv.y), pk2bf(xv.z, xv.w));
        *(uint2*)(Xs + r * 136 + f4 * 4) = o;
    }
    const uint4* wsrc = (const uint4*)(wt + (size_t)(mat * 3 + deg) * 16384);
    for (int e = tid; e < 1024; e += 256) {            // stage W half 0 (rows 0..63)
        int j = e >> 4, f8 = e & 15;
        *(uint4*)(Ws + j * 136 + f8 * 8) = wsrc[j * 16 + f8];
    }
    __syncthreads();

    const int w = tid >> 6, lane = tid & 63, quad = lane >> 4, lrow = lane & 15;

    if (mat == 2) {                    // ---- v path (original operand order) ----
        f32x4 acc[8];
#pragma unroll
        for (int ct = 0; ct < 8; ct++) acc[ct] = (f32x4){0.f, 0.f, 0.f, 0.f};
        for (int h = 0; h < 2; h++) {
            if (h) {
                for (int e = tid; e < 1024; e += 256) {
                    int j = e >> 4, f8 = e & 15;
                    *(uint4*)(Ws + j * 136 + f8 * 8) = wsrc[(64 + j) * 16 + f8];
                }
                __syncthreads();
            }
#pragma unroll
            for (int ks = 0; ks < 4; ks++) {
                short8 a = *(const short8*)(Xs + (w * 16 + lrow) * 136 + ks * 32 + quad * 8);
#pragma unroll
                for (int c4 = 0; c4 < 4; c4++) {
                    short8 bfr = *(const short8*)(Ws + (c4 * 16 + lrow) * 136 + ks * 32 + quad * 8);
                    acc[h * 4 + c4] = __builtin_amdgcn_mfma_f32_16x16x32_bf16(a, bfr, acc[h * 4 + c4], 0, 0, 0);
                }
            }
            if (!h) __syncthreads();
        }
        float yv[8][4];
#pragma unroll
        for (int ct = 0; ct < 8; ct++)
#pragma unroll
            for (int r = 0; r < 4; r++) yv[ct][r] = acc[ct][r];

        u16* T = Ws;                   // 128 x 66 = 8448 <= 8704 elems
        const int nlb = w * 16 + quad * 4;
        __syncthreads();
#pragma unroll
        for (int ct = 0; ct < 8; ct++) {
            int j = ct * 16 + lrow;
            *(unsigned*)(T + j * 66 + nlb)     = pk2bf(yv[ct][0], yv[ct][1]);
            *(unsigned*)(T + j * 66 + nlb + 2) = pk2bf(yv[ct][2], yv[ct][3]);
        }
        __syncthreads();
        for (int e = tid; e < 1024; e += 256) {
            int d = e >> 3, c = e & 7;
            *(uint4*)(vt + (size_t)(m * 128 + d) * N_NODES + n0 + c * 8) =
                *(const uint4*)(T + d * 66 + c * 8);
        }
        return;
    }

    // ---- q/k path: swapped operands => C rows = features, cols = nodes ----
    f32x4 acc[8];
#pragma unroll
    for (int ct = 0; ct < 8; ct++) acc[ct] = (f32x4){0.f, 0.f, 0.f, 0.f};
    for (int h = 0; h < 2; h++) {
        if (h) {
            for (int e = tid; e < 1024; e += 256) {
                int j = e >> 4, f8 = e & 15;
                *(uint4*)(Ws + j * 136 + f8 * 8) = wsrc[(64 + j) * 16 + f8];
            }
            __syncthreads();
        }
#pragma unroll
        for (int ks = 0; ks < 4; ks++) {
            short8 bx = *(const short8*)(Xs + (w * 16 + lrow) * 136 + ks * 32 + quad * 8);
#pragma unroll
            for (int c4 = 0; c4 < 4; c4++) {
                short8 aw = *(const short8*)(Ws + (c4 * 16 + lrow) * 136 + ks * 32 + quad * 8);
                acc[h * 4 + c4] = __builtin_amdgcn_mfma_f32_16x16x32_bf16(aw, bx, acc[h * 4 + c4], 0, 0, 0);
            }
        }
        if (!h) __syncthreads();
    }

    // lane holds features f = ct*16 + quad*4 + r (r=0..3) of node w*16+lrow
    const float* bias = (mat == 0) ? bq : bk;
    float yv[8][4];
#pragma unroll
    for (int ct = 0; ct < 8; ct++) {
        float4 b4 = (m == 0) ? *(const float4*)(bias + ct * 16 + quad * 4)
                             : make_float4(0.f, 0.f, 0.f, 0.f);
        yv[ct][0] = acc[ct][0] + b4.x;
        yv[ct][1] = acc[ct][1] + b4.y;
        yv[ct][2] = acc[ct][2] + b4.z;
        yv[ct][3] = acc[ct][3] + b4.w;
    }

    const int node = w * 16 + lrow;
    float p3[3];
#pragma unroll
    for (int gp = 0; gp < 3; gp++) p3[gp] = posS[node * 3 + gp];

    u16* O0 = smem;                    // 64 x 136 (dw-stride 68 == 4 mod 32: free b64)
    u16* O1 = smem + 64 * 136;
    u16* dst = (mat == 0) ? qr : kr;
    const float K8 = 8.0f / 630.0f;
    const size_t GSTRIDE = (size_t)NDEG * N_NODES * 128;   // one g slab

    __syncthreads();                   // all waves done with Xs/Ws before overwrite

    for (int gp = 0; gp < 3; gp++) {
        float p = p3[gp];
#pragma unroll
        for (int ct = 0; ct < 8; ct++) {
            float ti = (float)(ct * 8 + quad * 2) * K8;   // theta for pair 0
            float s0, c0, s1, c1;
            __sincosf(p * ti, &s0, &c0);
            __sincosf(p * (ti + K8), &s1, &c1);
            float y0 = yv[ct][0], y1 = yv[ct][1], y2 = yv[ct][2], y3 = yv[ct][3];
            // +dir: out_even = y0 c - y1 s ; out_odd = y1 c + y0 s
            unsigned w0p = pk2bf(y0 * c0 - y1 * s0, y1 * c0 + y0 * s0);
            unsigned w1p = pk2bf(y2 * c1 - y3 * s1, y3 * c1 + y2 * s1);
            // -dir (sin -> -sin)
            unsigned w0m = pk2bf(y0 * c0 + y1 * s0, y1 * c0 - y0 * s0);
            unsigned w1m = pk2bf(y2 * c1 + y3 * s1, y3 * c1 - y2 * s1);
            int off = node * 136 + ct * 16 + quad * 4;    // 8B-aligned
            *(uint2*)(O0 + off) = make_uint2(w0p, w1p);
            *(uint2*)(O1 + off) = make_uint2(w0m, w1m);
        }
        // wave-local store: contiguous 16KB slab per (gp,dir) across the block
        size_t sb = ((size_t)(gp * 2 * NDEG + m) * N_NODES + n0) * 128;
#pragma unroll
        for (int it = 0; it < 4; it++) {
            int slot = it * 64 + lane;
            int nl = w * 16 + (slot >> 4), cc = slot & 15;
            size_t o0 = sb + (size_t)nl * 128 + cc * 8;
            *(uint4*)(dst + o0)           = *(const uint4*)(O0 + nl * 136 + cc * 8);
            *(uint4*)(dst + o0 + GSTRIDE) = *(const uint4*)(O1 + nl * 136 + cc * 8);
        }
    }
}

// ---------------- kernel 3: Apart[g*2+kh] = qr_g · kr_g^T  (128x128, Ksplit2) ----
// 768 blocks = 96 (b,g) x 4 tiles x 2 k-halves = 3 blocks/CU exactly.
// Slab layout: per kc, m-slab = kk>>7, sub = kk&127; row stride 128 (256B dense).
// Staging: global_load_lds 16B/lane into linear LDS [128][64]; sigma2 swizzle
// (col ^= ((row>>2)&3)<<4) pre-applied on the GLOBAL source and on frag READS.
__global__ __launch_bounds__(256) void k_gemm1(const u16* __restrict__ qr,
                                               const u16* __restrict__ kr,
                                               u16* __restrict__ Apart) {
    int idx = blockIdx.x;              // 0..767
    int c   = idx & 7;                 // XCD id under round-robin-8
    int u   = idx >> 3;                // 0..95
    int t   = u & 3;                   // tile within combo
    int combo = (u >> 2) * 8 + c;      // 0..191
    int kh  = combo & 1;
    int bg  = combo >> 1;              // 0..95
    int g   = bg >> 4, b = bg & 15;
    int tr  = t >> 1, tc = t & 1;

    int qn0 = b * NB + tr * 128, kn0 = b * NB + tc * 128;
    int tid = threadIdx.x;
    __shared__ u16 Qs[128 * 64];       // linear, swizzled content
    __shared__ u16 Ks[128 * 64];
    int w = tid >> 6, lane = tid & 63, quad = lane >> 4, lrow = lane & 15;
    int l8 = lane >> 3, c8 = (lane & 7) * 8, lhi = lane >> 5;

    f32x4 acc[2][8];
#pragma unroll
    for (int at = 0; at < 2; at++)
#pragma unroll
        for (int ct = 0; ct < 8; ct++) acc[at][ct] = (f32x4){0.f, 0.f, 0.f, 0.f};

    u16* qdst = Qs + w * 32 * 64;      // wave-uniform LDS bases
    u16* kdst = Ks + w * 32 * 64;
    const int fs = ((lrow >> 2) & 3) << 4;   // frag-read swizzle (row-dependent via lrow)

    for (int kc = 0; kc < 9; kc++) {   // K half = 576 = 9 x 64
        int kk = kh * 576 + kc * 64;   // global k in 0..1151
        int ms = kk >> 7, sub = kk & 127;
        const u16* qb = qr + ((size_t)(g * NDEG + ms) * N_NODES + qn0) * 128 + sub;
        const u16* kb = kr + ((size_t)(g * NDEG + ms) * N_NODES + kn0) * 128 + sub;
#pragma unroll
        for (int s = 0; s < 4; s++) {  // wave w stages rows w*32+s*8 .. +8 of Q and K
            int row = w * 32 + s * 8 + l8;
            int sc  = c8 ^ (((2 * s + lhi) & 3) << 4);   // sigma2 on source col
            gl2lds16(qb + (size_t)row * 128 + sc, qdst + s * 8 * 64);
            gl2lds16(kb + (size_t)row * 128 + sc, kdst + s * 8 * 64);
        }
        __syncthreads();               // drains vmcnt(0) incl. global_load_lds
#pragma unroll
        for (int ks = 0; ks < 2; ks++) {
            int cs = (ks * 32 + quad * 8) ^ fs;
            int r0 = w * 32 + lrow;
            short8 a0 = *(const short8*)(Qs + r0 * 64 + cs);
            short8 a1 = *(const short8*)(Qs + (r0 + 16) * 64 + cs);
#pragma unroll
            for (int ct = 0; ct < 8; ct++) {
                short8 bfr = *(const short8*)(Ks + (ct * 16 + lrow) * 64 + cs);
                acc[0][ct] = __builtin_amdgcn_mfma_f32_16x16x32_bf16(a0, bfr, acc[0][ct], 0, 0, 0);
                acc[1][ct] = __builtin_amdgcn_mfma_f32_16x16x32_bf16(a1, bfr, acc[1][ct], 0, 0, 0);
            }
        }
        __syncthreads();
    }
    u16* dst = Apart + ((size_t)(g * 2 + kh) * NBATCH + b) * (NB * NB);
#pragma unroll
    for (int at = 0; at < 2; at++)
#pragma unroll
        for (int ct = 0; ct < 8; ct++)
#pragma unroll
            for (int r = 0; r < 4; r++) {
                int rib = tr * 128 + w * 32 + at * 16 + quad * 4 + r;
                int cib = tc * 128 + ct * 16 + lrow;
                dst[(size_t)rib * NB + cib] = f2bf(acc[at][ct][r]);
            }
}

// ---------------- kernel 3b: A2 = (1/6) sum_{12 partials} Apart[s]  (bf16) ---
__global__ __launch_bounds__(256) void k_asum(const u16* __restrict__ Ap,
                                              u16* __restrict__ A2) {
    size_t t = (size_t)blockIdx.x * 256 + threadIdx.x;   // uint4 index, < 131072
    float sacc[8];
#pragma unroll
    for (int i = 0; i < 8; i++) sacc[i] = 0.f;
#pragma unroll
    for (int s = 0; s < 12; s++) {
        uint4 v = *(const uint4*)(Ap + (size_t)s * ASLICE + t * 8);
        const unsigned* uu = (const unsigned*)&v;
#pragma unroll
        for (int h = 0; h < 4; h++) {
            sacc[h * 2]     += bf2f((u16)(uu[h] & 0xffff));
            sacc[h * 2 + 1] += bf2f((u16)(uu[h] >> 16));
        }
    }
    const float sc6 = 1.0f / 6.0f;
    unsigned o32[4];
#pragma unroll
    for (int i = 0; i < 4; i++) o32[i] = pk2bf(sacc[i * 2] * sc6, sacc[i * 2 + 1] * sc6);
    *(uint4*)(A2 + t * 8) = *(const uint4*)o32;
}

// ---------------- kernel 4: out = A2 · v  (+mask) ----------------------------
// 576 blocks 1-D, XCD-decoded: XCD c owns 8 (rt,b) pairs x all 9 dcb, so the
// 9 dcb blocks re-read their A-strip (32KB) from c's L2.
// R20: staging via global_load_lds(16B) + sigma2 swizzle (gemm1's proven pattern).
__global__ __launch_bounds__(256) void k_gemm2(const u16* __restrict__ A2,
                                               const u16* __restrict__ vt,
                                               const int* __restrict__ gmask,
                                               float* __restrict__ out) {
    int idx = blockIdx.x;              // 0..575
    int c   = idx & 7;                 // XCD id under round-robin-8
    int u   = idx >> 3;                // 0..71
    int pr9 = u / 9;                   // 0..7
    int dcb = u - pr9 * 9;             // 0..8
    int pair = pr9 * 8 + c;            // 0..63
    int rt  = pair >> 4, b = pair & 15;
    int d0 = dcb * 128;
    int tid = threadIdx.x;
    __shared__ u16 As[64 * 64];        // linear, swizzled content
    __shared__ u16 Vs[128 * 64];
    int w = tid >> 6, lane = tid & 63, quad = lane >> 4, lrow = lane & 15;
    int l8 = lane >> 3, c8 = (lane & 7) * 8, lhi = lane >> 5;

    f32x4 acc[8];
#pragma unroll
    for (int ct = 0; ct < 8; ct++) acc[ct] = (f32x4){0.f, 0.f, 0.f, 0.f};

    u16* adst = As + w * 16 * 64;      // wave-uniform LDS bases
    u16* vdst = Vs + w * 32 * 64;
    const u16* abase = A2 + (size_t)b * (NB * NB) + (size_t)(rt * 64) * NB;
    const u16* vbase = vt + (size_t)d0 * N_NODES + b * NB;
    const int fs = ((lrow >> 2) & 3) << 4;

    for (int kc = 0; kc < 4; kc++) {
        int k0 = kc * 64;
#pragma unroll
        for (int s = 0; s < 2; s++) {  // A: wave w stages rows w*16+s*8..+8
            int row = w * 16 + s * 8 + l8;
            int sc  = c8 ^ (((2 * s + lhi) & 3) << 4);
            gl2lds16(abase + (size_t)row * NB + k0 + sc, adst + s * 8 * 64);
        }
#pragma unroll
        for (int s = 0; s < 4; s++) {  // V: wave w stages rows w*32+s*8..+8
            int row = w * 32 + s * 8 + l8;
            int sc  = c8 ^ (((2 * s + lhi) & 3) << 4);
            gl2lds16(vbase + (size_t)row * N_NODES + k0 + sc, vdst + s * 8 * 64);
        }
        __syncthreads();
#pragma unroll
        for (int ks = 0; ks < 2; ks++) {
            int cs = (ks * 32 + quad * 8) ^ fs;
            short8 a = *(const short8*)(As + (w * 16 + lrow) * 64 + cs);
#pragma unroll
            for (int ct = 0; ct < 8; ct++) {
                short8 bfr = *(const short8*)(Vs + (ct * 16 + lrow) * 64 + cs);
                acc[ct] = __builtin_amdgcn_mfma_f32_16x16x32_bf16(a, bfr, acc[ct], 0, 0, 0);
            }
        }
        __syncthreads();
    }
    int mv = gmask[b];
#pragma unroll
    for (int ct = 0; ct < 8; ct++)
#pragma unroll
        for (int r = 0; r < 4; r++) {
            int node = b * NB + rt * 64 + w * 16 + quad * 4 + r;
            int d = d0 + ct * 16 + lrow;
            out[(size_t)node * MD + d] = mv ? acc[ct][r] : 0.0f;
        }
}

// ---------------- launch -----------------------------------------------------
extern "C" void kernel_launch(void* const* d_in, const int* in_sizes, int n_in,
                              void* d_out, int out_size, void* d_ws, size_t ws_size,
                              hipStream_t stream) {
    (void)in_sizes; (void)n_in; (void)out_size; (void)ws_size;

    const float* X    = (const float*)d_in[0];
    const float* pos  = (const float*)d_in[1];
    const int*   gmask= (const int*)  d_in[3];
    const float* Wq   = (const float*)d_in[4];
    const float* bq   = (const float*)d_in[5];
    const float* Wk   = (const float*)d_in[6];
    const float* bk   = (const float*)d_in[7];
    const float* Wv   = (const float*)d_in[8];
    const float* bv   = (const float*)d_in[9];
    float* out = (float*)d_out;
    (void)bv;

    char* ws = (char*)d_ws;
    u16*   wt   = (u16*)  (ws + OFF_WT);
    u16*   qrp  = (u16*)  (ws + OFF_QR);
    u16*   krp  = (u16*)  (ws + OFF_KR);
    u16*   vtp  = (u16*)  (ws + OFF_VT);
    u16*   App  = (u16*)  (ws + OFF_AP);
    u16*   a2p  = (u16*)  (ws + OFF_A2);    // alias of qrp (timeline-disjoint)

    k_prep <<<dim3(36),         dim3(256), 0, stream>>>(Wq, Wk, Wv, wt);
    k_qkv  <<<dim3(64, 9, 3),   dim3(256), 0, stream>>>(X, wt, bq, bk, bv, pos, qrp, krp, vtp);
    k_gemm1<<<dim3(768),        dim3(256), 0, stream>>>(qrp, krp, App);
    k_asum <<<dim3(512),        dim3(256), 0, stream>>>(App, a2p);
    k_gemm2<<<dim3(576),        dim3(256), 0, stream>>>(a2p, vtp, gmask, out);
}